// Round 3
// baseline (276.774 us; speedup 1.0000x reference)
//
#include <hip/hip_runtime.h>

// VectorQuantizer R12: pre-split z + single-buffer DMA gemm at 5 blocks/CU.
//   wh = f16(16*w_hat), wl = f16(16*w_hat - wh)   (uniform x16: argmax-invariant)
//   zh = f16(4*z),      zl = f16(4*z - zh)        (uniform x4:  argmax-invariant)
//   dot = hh + hl + lh  (single f32 accumulator chain; ll ~2^-22 rel, dropped)
// argmin_k ||z_hat - w_hat_k|| == argmax_k <z, w_hat_k>  -> only codebook normalized.
//
// R10/R11 post-mortem: dbuf (67.5 KB LDS) cut occupancy to 2 blocks/CU and
// BOTH barrier-drain (R10) and counted-vmcnt (R11) variants sat at ~108 us,
// MfmaUtil 19% -- latency-bound, nothing to interleave. R9 (4 blocks/CU,
// naive 2-barrier loop) was 78.5 us: TLP is the latency hider here, not
// intra-block pipelining. R12 = R9 structure, pure-DMA A and B (VALU split
// work already moved to prep), LDS shrunk to EXACTLY 32 KB (epilogue red
// arrays overlaid on the dead stage buffer) -> 5 blocks/CU, 20 waves/CU.

typedef _Float16 half8 __attribute__((ext_vector_type(8)));
typedef float    floatx4 __attribute__((ext_vector_type(4)));

#define C_DIM 256
#define K_CODES 1024
#define HW 1024
#define NPIX 32768
#define NTILES 8          // 1024 / 128 candidate tiles per pixel
#define USTR 512          // unit stride in f16 (16 rows x 32 k, DMA-linear)

#define GLOAD_LDS16(g, l) __builtin_amdgcn_global_load_lds(                    \
    (const __attribute__((address_space(1))) unsigned int*)(g),                \
    (__attribute__((address_space(3))) unsigned int*)(l), 16, 0, 0)

// ---------------- kernel 1: norm codebook  +  z transpose/split -------------
// blocks 0..1023: w-row normalize + x16 f16 split (unchanged math).
// blocks 1024..1535: 64-pixel tile of z: read coalesced along HW, split,
//   transpose via LDS, write zh/zl [pix][C] (k-contiguous for gemm DMA).
__global__ __launch_bounds__(256) void vq_prep(
        const float* __restrict__ z, const float* __restrict__ w,
        float* __restrict__ w_n, _Float16* __restrict__ wh, _Float16* __restrict__ wl,
        _Float16* __restrict__ zh, _Float16* __restrict__ zl) {
    __shared__ float wsum[4];
    __shared__ unsigned pk[64][257];   // h | l<<16 ; stride 257: 2-way-free writes
    const int t = threadIdx.x;

    if (blockIdx.x < K_CODES) {
        const int row = blockIdx.x;
        float x = w[row * C_DIM + t];
        float s = x * x;
        #pragma unroll
        for (int off = 32; off > 0; off >>= 1) s += __shfl_down(s, off, 64);
        if ((t & 63) == 0) wsum[t >> 6] = s;
        __syncthreads();
        float tot = wsum[0] + wsum[1] + wsum[2] + wsum[3];
        float inv = 1.0f / fmaxf(sqrtf(tot), 1e-12f);
        float y = x * inv;
        w_n[row * C_DIM + t] = y;          // row-major: finalize reads rows coalesced
        float ys = 16.0f * y;
        _Float16 hi = (_Float16)ys;
        wh[row * C_DIM + t] = hi;
        wl[row * C_DIM + t] = (_Float16)(ys - (float)hi);
        return;
    }

    const int zb = blockIdx.x - K_CODES;   // 0..511
    const int pg = zb * 64;                // global pixel base
    const int b  = pg >> 10, p0 = pg & 1023;
    const float* zp = z + (size_t)b * C_DIM * HW + p0;

    // stage 1: read [16 c x 64 p] per iter, coalesced along p; split; LDS
    const int cc = t >> 4, pp = (t & 15) * 4;
    #pragma unroll
    for (int it = 0; it < 16; it++) {
        const int c = it * 16 + cc;
        floatx4 v = *(const floatx4*)(zp + (size_t)c * HW + pp);
        #pragma unroll
        for (int j = 0; j < 4; j++) {
            float xs = 4.0f * v[j];                 // same scale/path as R9 ->
            _Float16 h = (_Float16)xs;              // bitwise-identical operands
            _Float16 l = (_Float16)(xs - (float)h);
            pk[pp + j][c] = (unsigned)__builtin_bit_cast(unsigned short, h)
                          | ((unsigned)__builtin_bit_cast(unsigned short, l) << 16);
        }
    }
    __syncthreads();

    // stage 2: per iter 16 pixels x 16-half chunks, stores coalesced along c
    const int pl = t >> 4, c0 = (t & 15) * 16;
    #pragma unroll
    for (int it = 0; it < 4; it++) {
        const int p = it * 16 + pl;
        half8 hv0, hv1, lv0, lv1;
        #pragma unroll
        for (int s = 0; s < 8; s++) {
            unsigned u0 = pk[p][c0 + s];
            unsigned u1 = pk[p][c0 + 8 + s];
            hv0[s] = __builtin_bit_cast(_Float16, (unsigned short)(u0 & 0xffffu));
            lv0[s] = __builtin_bit_cast(_Float16, (unsigned short)(u0 >> 16));
            hv1[s] = __builtin_bit_cast(_Float16, (unsigned short)(u1 & 0xffffu));
            lv1[s] = __builtin_bit_cast(_Float16, (unsigned short)(u1 >> 16));
        }
        const size_t base = (size_t)(pg + p) * C_DIM + c0;
        *(half8*)(zh + base)     = hv0;
        *(half8*)(zh + base + 8) = hv1;
        *(half8*)(zl + base)     = lv0;
        *(half8*)(zl + base + 8) = lv1;
    }
}

// ---------------- kernel 2: single-buffer DMA MFMA GEMM + argmax ------------
// grid (256 m-tiles, 8 n-tiles), 256 thr = 4 waves 2x2; wave tile 64x64.
// BK=32, 8 kt. Per kt: bar; wave DMAs its plane (8 x 1KB); bar (vmcnt drain
// -> staged); ds_read frags; 48 MFMA. LDS = exactly 32 KB (red arrays
// overlaid on stage buffer after the loop) -> 5 blocks/CU hide the drain.
__global__ __launch_bounds__(256, 5) void vq_gemm(
        const _Float16* __restrict__ zh, const _Float16* __restrict__ zl,
        const _Float16* __restrict__ wh, const _Float16* __restrict__ wl,
        float* __restrict__ cand_val, int* __restrict__ cand_idx) {
    __shared__ _Float16 S[4][8 * USTR];      // {Ah,Al,Bh,Bl} x 8KB = 32 KB exact
    float* red_v = (float*)&S[0][0];         // [128][2], overlaid (dead after loop)
    int*   red_i = (int*)&S[0][1024];        // [128][2]

    const int tid  = threadIdx.x;
    const int lane = tid & 63, wave = tid >> 6;
    const int wm = wave >> 1, wn = wave & 1;
    const int quad = lane >> 4, l15 = lane & 15;
    const int m0 = blockIdx.x * 128, n0 = blockIdx.y * 128;

    // DMA: wave = plane {0:Ah 1:Al 2:Bh 3:Bl}, 8 units each; lane -> (row l15, k-chunk quad)
    const _Float16* ph  = (wave & 2) ? wh : zh;
    const _Float16* pl_ = (wave & 2) ? wl : zl;
    const _Float16* pbase = (wave & 1) ? pl_ : ph;
    const int rbase = (wave & 2) ? n0 : m0;
    const _Float16* gsrc = pbase + (size_t)(rbase + l15) * C_DIM + quad * 8;

    floatx4 acc[4][4];
    #pragma unroll
    for (int i = 0; i < 4; i++)
        #pragma unroll
        for (int j = 0; j < 4; j++) acc[i][j] = (floatx4){0.f, 0.f, 0.f, 0.f};

    const int afrag = wm * 4, bfrag = wn * 4;

    for (int kt = 0; kt < 8; kt++) {
        __syncthreads();                     // all waves done reading kt-1 frags
        {   const _Float16* g_ = gsrc + kt * 32;
            _Float16* l_ = &S[wave][0];
            #pragma unroll
            for (int u = 0; u < 8; u++)
                GLOAD_LDS16(g_ + (size_t)u * (16 * C_DIM), l_ + u * USTR);
        }
        __syncthreads();                     // vmcnt(0) drain -> buffer staged

        half8 ah[4], al[4], bh[4], bl[4];
        #pragma unroll
        for (int i = 0; i < 4; i++) {
            ah[i] = *(const half8*)&S[0][(afrag + i) * USTR + lane * 8];
            al[i] = *(const half8*)&S[1][(afrag + i) * USTR + lane * 8];
            bh[i] = *(const half8*)&S[2][(bfrag + i) * USTR + lane * 8];
            bl[i] = *(const half8*)&S[3][(bfrag + i) * USTR + lane * 8];
        }
        #pragma unroll
        for (int mi = 0; mi < 4; mi++)
            #pragma unroll
            for (int ni = 0; ni < 4; ni++) {
                acc[mi][ni] = __builtin_amdgcn_mfma_f32_16x16x32_f16(ah[mi], bh[ni], acc[mi][ni], 0, 0, 0);
                acc[mi][ni] = __builtin_amdgcn_mfma_f32_16x16x32_f16(ah[mi], bl[ni], acc[mi][ni], 0, 0, 0);
                acc[mi][ni] = __builtin_amdgcn_mfma_f32_16x16x32_f16(al[mi], bh[ni], acc[mi][ni], 0, 0, 0);
            }
    }

    __syncthreads();     // stage buffer dead; safe to overlay red arrays

    // epilogue: per-lane best over ni, shfl-reduce over quad's 16 lanes
    #pragma unroll
    for (int mi = 0; mi < 4; mi++) {
        #pragma unroll
        for (int r = 0; r < 4; r++) {
            float bv = -__builtin_inff();
            int   bi = 0x7fffffff;
            #pragma unroll
            for (int ni = 0; ni < 4; ni++) {
                float v = acc[mi][ni][r];
                int  ci = n0 + wn * 64 + ni * 16 + l15;
                if (v > bv || (v == bv && ci < bi)) { bv = v; bi = ci; }
            }
            #pragma unroll
            for (int mk = 8; mk; mk >>= 1) {
                float ov = __shfl_xor(bv, mk, 16);
                int   oi = __shfl_xor(bi, mk, 16);
                if (ov > bv || (ov == bv && oi < bi)) { bv = ov; bi = oi; }
            }
            if (l15 == 0) {
                int row = wm * 64 + mi * 16 + quad * 4 + r;  // C/D: row=(lane>>4)*4+reg
                red_v[row * 2 + wn] = bv;
                red_i[row * 2 + wn] = bi;
            }
        }
    }
    __syncthreads();
    if (tid < 128) {
        float bv = red_v[tid * 2 + 0]; int bi = red_i[tid * 2 + 0];
        float v2 = red_v[tid * 2 + 1]; int i2 = red_i[tid * 2 + 1];
        if (v2 > bv || (v2 == bv && i2 < bi)) { bv = v2; bi = i2; }
        const int pix = m0 + tid;
        cand_val[(size_t)pix * NTILES + blockIdx.y] = bv;
        cand_idx[(size_t)pix * NTILES + blockIdx.y] = bi;
    }
}

// ---------------- kernel 3: gather-free finalize (unchanged, verified) ------
__global__ __launch_bounds__(256) void vq_finalize(
        const float* __restrict__ cand_val,
        const int*   __restrict__ cand_idx,
        const float* __restrict__ w_n,   // [1024][256] row-major
        float* __restrict__ zq,          // [32][256][1024]
        float* __restrict__ idx_out) {   // [32768] as float
    __shared__ float tile[64][257];      // 65.8 KB, +1 pad -> conflict-free
    __shared__ int   idx_s[64];
    const int t    = threadIdx.x;
    const int lane = t & 63, wave = t >> 6;
    const int n0   = blockIdx.x * 64;    // global pixel base
    const int b    = n0 >> 10, p0 = n0 & 1023;

    if (t < 64) {
        const int n = n0 + t;
        const size_t base = (size_t)n * NTILES;
        float bv = cand_val[base]; int bi = cand_idx[base];
        #pragma unroll
        for (int j = 1; j < NTILES; j++) {
            float v = cand_val[base + j];
            int   c = cand_idx[base + j];
            if (v > bv || (v == bv && c < bi)) { bv = v; bi = c; }
        }
        idx_s[t] = bi;
        idx_out[n] = (float)bi;
    }
    __syncthreads();
    // (b) wave w loads rows for pixels w*16..+15: 1 KB coalesced per row
    #pragma unroll
    for (int i = 0; i < 16; i++) {
        const int p = wave * 16 + i;
        const int row = idx_s[p];        // wave-uniform broadcast
        floatx4 v = *(const floatx4*)(w_n + (size_t)row * C_DIM + lane * 4);
        *(floatx4*)&tile[p][lane * 4] = v;
    }
    __syncthreads();
    // (c) stores: float4 along pixels; per wave-store 4 c-values x 64 px
    float* zqb = zq + (size_t)b * (C_DIM * HW) + p0;
    #pragma unroll
    for (int it = 0; it < 16; it++) {
        const int c = it * 16 + wave * 4 + (lane >> 4);   // 0..255
        const int p = (lane & 15) * 4;
        floatx4 v = { tile[p][c], tile[p + 1][c], tile[p + 2][c], tile[p + 3][c] };
        *(floatx4*)(zqb + (size_t)c * HW + p) = v;
    }
}

// ---------------- launcher --------------------------------------------------
extern "C" void kernel_launch(void* const* d_in, const int* in_sizes, int n_in,
                              void* d_out, int out_size, void* d_ws, size_t ws_size,
                              hipStream_t stream) {
    const float* z = (const float*)d_in[0];   // 32*256*32*32
    const float* w = (const float*)d_in[1];   // 1024*256
    float* out     = (float*)d_out;           // z_q (8388608) ++ indices (32768)

    char* ws = (char*)d_ws;                              // 36 MB used
    _Float16* zh   = (_Float16*)(ws);                    //  0 .. 16 MB
    _Float16* zl   = (_Float16*)(ws + (16u << 20));      // 16 .. 32 MB
    float*    w_n  = (float*)(ws + (32u << 20));         // 32 .. 33 MB
    _Float16* wh   = (_Float16*)(ws + (33u << 20));      // 33 .. 33.5 MB
    _Float16* wl   = (_Float16*)(ws + (33u << 20) + (1u << 19)); // 33.5 .. 34 MB
    float*    cval = (float*)(ws + (34u << 20));         // 34 .. 35 MB
    int*      cidx = (int*)(ws + (35u << 20));           // 35 .. 36 MB

    vq_prep<<<K_CODES + NPIX / 64, 256, 0, stream>>>(z, w, w_n, wh, wl, zh, zl);
    vq_gemm<<<dim3(NPIX / 128, NTILES), 256, 0, stream>>>(zh, zl, wh, wl, cval, cidx);
    vq_finalize<<<NPIX / 64, 256, 0, stream>>>(cval, cidx, w_n, out, out + 8388608);
}

// Round 4
// 171.835 us; speedup vs baseline: 1.6107x; 1.6107x over previous
//
#include <hip/hip_runtime.h>

// VectorQuantizer R13: R9 schedule (single-buf, 4 blocks/CU) + pure-DMA staging.
//   wh = f16(16*w_hat), wl = f16(16*w_hat - wh)   (uniform x16: argmax-invariant)
//   zh = f16(4*z),      zl = f16(4*z - zh)        (uniform x4:  argmax-invariant)
//   dot = hh + hl + lh  (single f32 accumulator chain; ll ~2^-22 rel, dropped)
// argmin_k ||z_hat - w_hat_k|| == argmax_k <z, w_hat_k>  -> only codebook normalized.
//
// R12 post-mortem: __launch_bounds__(256,5) capped unified VGPR+AGPR at ~102
// -> accumulator spill (WRITE_SIZE 331 MB scratch). R13 uses bound 4 (=128
// regs/wave, proven by R9) and shrinks peak frag liveness: B frags resident
// (32 VGPR), A frags streamed per-mi (8 VGPR). acc 64 AGPR + ~45 VGPR fits.
// Schedule = R9's proven 2-barrier/kt loop; staging = global_load_lds only.

typedef _Float16 half8 __attribute__((ext_vector_type(8)));
typedef float    floatx4 __attribute__((ext_vector_type(4)));

#define C_DIM 256
#define K_CODES 1024
#define HW 1024
#define NPIX 32768
#define NTILES 8          // 1024 / 128 candidate tiles per pixel
#define USTR 512          // unit stride in f16 (16 rows x 32 k, DMA-linear)

#define GLOAD_LDS16(g, l) __builtin_amdgcn_global_load_lds(                    \
    (const __attribute__((address_space(1))) unsigned int*)(g),                \
    (__attribute__((address_space(3))) unsigned int*)(l), 16, 0, 0)

// ---------------- kernel 1: norm codebook  +  z transpose/split -------------
// blocks 0..1023: w-row normalize + x16 f16 split (unchanged math).
// blocks 1024..1535: 64-pixel tile of z: read coalesced along HW, split,
//   transpose via LDS, write zh/zl [pix][C] (k-contiguous for gemm DMA).
__global__ __launch_bounds__(256) void vq_prep(
        const float* __restrict__ z, const float* __restrict__ w,
        float* __restrict__ w_n, _Float16* __restrict__ wh, _Float16* __restrict__ wl,
        _Float16* __restrict__ zh, _Float16* __restrict__ zl) {
    __shared__ float wsum[4];
    __shared__ unsigned pk[64][257];   // h | l<<16 ; stride 257: 2-way-free writes
    const int t = threadIdx.x;

    if (blockIdx.x < K_CODES) {
        const int row = blockIdx.x;
        float x = w[row * C_DIM + t];
        float s = x * x;
        #pragma unroll
        for (int off = 32; off > 0; off >>= 1) s += __shfl_down(s, off, 64);
        if ((t & 63) == 0) wsum[t >> 6] = s;
        __syncthreads();
        float tot = wsum[0] + wsum[1] + wsum[2] + wsum[3];
        float inv = 1.0f / fmaxf(sqrtf(tot), 1e-12f);
        float y = x * inv;
        w_n[row * C_DIM + t] = y;          // row-major: finalize reads rows coalesced
        float ys = 16.0f * y;
        _Float16 hi = (_Float16)ys;
        wh[row * C_DIM + t] = hi;
        wl[row * C_DIM + t] = (_Float16)(ys - (float)hi);
        return;
    }

    const int zb = blockIdx.x - K_CODES;   // 0..511
    const int pg = zb * 64;                // global pixel base
    const int b  = pg >> 10, p0 = pg & 1023;
    const float* zp = z + (size_t)b * C_DIM * HW + p0;

    // stage 1: read [16 c x 64 p] per iter, coalesced along p; split; LDS
    const int cc = t >> 4, pp = (t & 15) * 4;
    #pragma unroll
    for (int it = 0; it < 16; it++) {
        const int c = it * 16 + cc;
        floatx4 v = *(const floatx4*)(zp + (size_t)c * HW + pp);
        #pragma unroll
        for (int j = 0; j < 4; j++) {
            float xs = 4.0f * v[j];                 // same scale/path as R9 ->
            _Float16 h = (_Float16)xs;              // bitwise-identical operands
            _Float16 l = (_Float16)(xs - (float)h);
            pk[pp + j][c] = (unsigned)__builtin_bit_cast(unsigned short, h)
                          | ((unsigned)__builtin_bit_cast(unsigned short, l) << 16);
        }
    }
    __syncthreads();

    // stage 2: per iter 16 pixels x 16-half chunks, stores coalesced along c
    const int pl = t >> 4, c0 = (t & 15) * 16;
    #pragma unroll
    for (int it = 0; it < 4; it++) {
        const int p = it * 16 + pl;
        half8 hv0, hv1, lv0, lv1;
        #pragma unroll
        for (int s = 0; s < 8; s++) {
            unsigned u0 = pk[p][c0 + s];
            unsigned u1 = pk[p][c0 + 8 + s];
            hv0[s] = __builtin_bit_cast(_Float16, (unsigned short)(u0 & 0xffffu));
            lv0[s] = __builtin_bit_cast(_Float16, (unsigned short)(u0 >> 16));
            hv1[s] = __builtin_bit_cast(_Float16, (unsigned short)(u1 & 0xffffu));
            lv1[s] = __builtin_bit_cast(_Float16, (unsigned short)(u1 >> 16));
        }
        const size_t base = (size_t)(pg + p) * C_DIM + c0;
        *(half8*)(zh + base)     = hv0;
        *(half8*)(zh + base + 8) = hv1;
        *(half8*)(zl + base)     = lv0;
        *(half8*)(zl + base + 8) = lv1;
    }
}

// ---------------- kernel 2: single-buffer DMA MFMA GEMM + argmax ------------
// grid (256 m-tiles, 8 n-tiles), 256 thr = 4 waves 2x2; wave tile 64x64.
// BK=32, 8 kt. Per kt: bar; wave DMAs its plane (8 x 1KB); bar; B frags
// resident, A frags streamed per-mi; 48 MFMA. 32 KB LDS + <=128 regs/wave
// -> 4 blocks/CU; cross-block TLP hides the staging drain (R9-proven).
__global__ __launch_bounds__(256, 4) void vq_gemm(
        const _Float16* __restrict__ zh, const _Float16* __restrict__ zl,
        const _Float16* __restrict__ wh, const _Float16* __restrict__ wl,
        float* __restrict__ cand_val, int* __restrict__ cand_idx) {
    __shared__ _Float16 S[4][8 * USTR];      // {Ah,Al,Bh,Bl} x 8KB = 32 KB exact
    float* red_v = (float*)&S[0][0];         // [128][2], overlaid (dead after loop)
    int*   red_i = (int*)&S[0][1024];        // [128][2]

    const int tid  = threadIdx.x;
    const int lane = tid & 63, wave = tid >> 6;
    const int wm = wave >> 1, wn = wave & 1;
    const int quad = lane >> 4, l15 = lane & 15;
    const int m0 = blockIdx.x * 128, n0 = blockIdx.y * 128;

    // DMA: wave = plane {0:Ah 1:Al 2:Bh 3:Bl}, 8 units each; lane -> (row l15, k-chunk quad)
    const _Float16* ph  = (wave & 2) ? wh : zh;
    const _Float16* pl_ = (wave & 2) ? wl : zl;
    const _Float16* pbase = (wave & 1) ? pl_ : ph;
    const int rbase = (wave & 2) ? n0 : m0;
    const _Float16* gsrc = pbase + (size_t)(rbase + l15) * C_DIM + quad * 8;

    floatx4 acc[4][4];
    #pragma unroll
    for (int i = 0; i < 4; i++)
        #pragma unroll
        for (int j = 0; j < 4; j++) acc[i][j] = (floatx4){0.f, 0.f, 0.f, 0.f};

    const int afrag = wm * 4, bfrag = wn * 4;

    for (int kt = 0; kt < 8; kt++) {
        __syncthreads();                     // all waves done reading kt-1 frags
        {   const _Float16* g_ = gsrc + kt * 32;
            _Float16* l_ = &S[wave][0];
            #pragma unroll
            for (int u = 0; u < 8; u++)
                GLOAD_LDS16(g_ + (size_t)u * (16 * C_DIM), l_ + u * USTR);
        }
        __syncthreads();                     // vmcnt(0) drain -> buffer staged

        // B frags resident (32 VGPR, shared across both m-rows of this wave)
        half8 bh[4], bl[4];
        #pragma unroll
        for (int i = 0; i < 4; i++) {
            bh[i] = *(const half8*)&S[2][(bfrag + i) * USTR + lane * 8];
            bl[i] = *(const half8*)&S[3][(bfrag + i) * USTR + lane * 8];
        }
        // A frags streamed per-mi (8 VGPR live) -> peak regs fit 128/wave
        #pragma unroll
        for (int mi = 0; mi < 4; mi++) {
            half8 ah = *(const half8*)&S[0][(afrag + mi) * USTR + lane * 8];
            half8 al = *(const half8*)&S[1][(afrag + mi) * USTR + lane * 8];
            #pragma unroll
            for (int ni = 0; ni < 4; ni++) {
                acc[mi][ni] = __builtin_amdgcn_mfma_f32_16x16x32_f16(ah, bh[ni], acc[mi][ni], 0, 0, 0);
                acc[mi][ni] = __builtin_amdgcn_mfma_f32_16x16x32_f16(ah, bl[ni], acc[mi][ni], 0, 0, 0);
                acc[mi][ni] = __builtin_amdgcn_mfma_f32_16x16x32_f16(al, bh[ni], acc[mi][ni], 0, 0, 0);
            }
        }
    }

    __syncthreads();     // stage buffer dead; safe to overlay red arrays

    // epilogue: per-lane best over ni, shfl-reduce over quad's 16 lanes
    #pragma unroll
    for (int mi = 0; mi < 4; mi++) {
        #pragma unroll
        for (int r = 0; r < 4; r++) {
            float bv = -__builtin_inff();
            int   bi = 0x7fffffff;
            #pragma unroll
            for (int ni = 0; ni < 4; ni++) {
                float v = acc[mi][ni][r];
                int  ci = n0 + wn * 64 + ni * 16 + l15;
                if (v > bv || (v == bv && ci < bi)) { bv = v; bi = ci; }
            }
            #pragma unroll
            for (int mk = 8; mk; mk >>= 1) {
                float ov = __shfl_xor(bv, mk, 16);
                int   oi = __shfl_xor(bi, mk, 16);
                if (ov > bv || (ov == bv && oi < bi)) { bv = ov; bi = oi; }
            }
            if (l15 == 0) {
                int row = wm * 64 + mi * 16 + quad * 4 + r;  // C/D: row=(lane>>4)*4+reg
                red_v[row * 2 + wn] = bv;
                red_i[row * 2 + wn] = bi;
            }
        }
    }
    __syncthreads();
    if (tid < 128) {
        float bv = red_v[tid * 2 + 0]; int bi = red_i[tid * 2 + 0];
        float v2 = red_v[tid * 2 + 1]; int i2 = red_i[tid * 2 + 1];
        if (v2 > bv || (v2 == bv && i2 < bi)) { bv = v2; bi = i2; }
        const int pix = m0 + tid;
        cand_val[(size_t)pix * NTILES + blockIdx.y] = bv;
        cand_idx[(size_t)pix * NTILES + blockIdx.y] = bi;
    }
}

// ---------------- kernel 3: gather-free finalize (unchanged, verified) ------
__global__ __launch_bounds__(256) void vq_finalize(
        const float* __restrict__ cand_val,
        const int*   __restrict__ cand_idx,
        const float* __restrict__ w_n,   // [1024][256] row-major
        float* __restrict__ zq,          // [32][256][1024]
        float* __restrict__ idx_out) {   // [32768] as float
    __shared__ float tile[64][257];      // 65.8 KB, +1 pad -> conflict-free
    __shared__ int   idx_s[64];
    const int t    = threadIdx.x;
    const int lane = t & 63, wave = t >> 6;
    const int n0   = blockIdx.x * 64;    // global pixel base
    const int b    = n0 >> 10, p0 = n0 & 1023;

    if (t < 64) {
        const int n = n0 + t;
        const size_t base = (size_t)n * NTILES;
        float bv = cand_val[base]; int bi = cand_idx[base];
        #pragma unroll
        for (int j = 1; j < NTILES; j++) {
            float v = cand_val[base + j];
            int   c = cand_idx[base + j];
            if (v > bv || (v == bv && c < bi)) { bv = v; bi = c; }
        }
        idx_s[t] = bi;
        idx_out[n] = (float)bi;
    }
    __syncthreads();
    // (b) wave w loads rows for pixels w*16..+15: 1 KB coalesced per row
    #pragma unroll
    for (int i = 0; i < 16; i++) {
        const int p = wave * 16 + i;
        const int row = idx_s[p];        // wave-uniform broadcast
        floatx4 v = *(const floatx4*)(w_n + (size_t)row * C_DIM + lane * 4);
        *(floatx4*)&tile[p][lane * 4] = v;
    }
    __syncthreads();
    // (c) stores: float4 along pixels; per wave-store 4 c-values x 64 px
    float* zqb = zq + (size_t)b * (C_DIM * HW) + p0;
    #pragma unroll
    for (int it = 0; it < 16; it++) {
        const int c = it * 16 + wave * 4 + (lane >> 4);   // 0..255
        const int p = (lane & 15) * 4;
        floatx4 v = { tile[p][c], tile[p + 1][c], tile[p + 2][c], tile[p + 3][c] };
        *(floatx4*)(zqb + (size_t)c * HW + p) = v;
    }
}

// ---------------- launcher --------------------------------------------------
extern "C" void kernel_launch(void* const* d_in, const int* in_sizes, int n_in,
                              void* d_out, int out_size, void* d_ws, size_t ws_size,
                              hipStream_t stream) {
    const float* z = (const float*)d_in[0];   // 32*256*32*32
    const float* w = (const float*)d_in[1];   // 1024*256
    float* out     = (float*)d_out;           // z_q (8388608) ++ indices (32768)

    char* ws = (char*)d_ws;                              // 36 MB used
    _Float16* zh   = (_Float16*)(ws);                    //  0 .. 16 MB
    _Float16* zl   = (_Float16*)(ws + (16u << 20));      // 16 .. 32 MB
    float*    w_n  = (float*)(ws + (32u << 20));         // 32 .. 33 MB
    _Float16* wh   = (_Float16*)(ws + (33u << 20));      // 33 .. 33.5 MB
    _Float16* wl   = (_Float16*)(ws + (33u << 20) + (1u << 19)); // 33.5 .. 34 MB
    float*    cval = (float*)(ws + (34u << 20));         // 34 .. 35 MB
    int*      cidx = (int*)(ws + (35u << 20));           // 35 .. 36 MB

    vq_prep<<<K_CODES + NPIX / 64, 256, 0, stream>>>(z, w, w_n, wh, wl, zh, zl);
    vq_gemm<<<dim3(NPIX / 128, NTILES), 256, 0, stream>>>(zh, zl, wh, wl, cval, cidx);
    vq_finalize<<<NPIX / 64, 256, 0, stream>>>(cval, cidx, w_n, out, out + 8388608);
}

// Round 5
// 161.070 us; speedup vs baseline: 1.7184x; 1.0668x over previous
//
#include <hip/hip_runtime.h>

// VectorQuantizer R14: barrier-free gemm — frag-ordered operands, direct
// per-lane register loads, 2-deep software pipeline, no LDS staging.
//   wh = f16(16*w_hat), wl = f16(16*w_hat - wh)   (uniform x16: argmax-invariant)
//   zh = f16(4*z),      zl = f16(4*z - zh)        (uniform x4:  argmax-invariant)
//   dot = hh + hl + lh  (single f32 accumulator chain; ll ~2^-22 rel, dropped)
// argmin_k ||z_hat - w_hat_k|| == argmax_k <z, w_hat_k>  -> only codebook normalized.
//
// R9..R13 post-mortem: every LDS-staged variant pinned at ~78-110 us with
// MfmaUtil 19-27% regardless of VALU work / conflicts / occupancy. The
// invariant = per-kt {bar; DMA; vmcnt(0) bar; compute} exposing full staging
// latency to all waves. LDS only deduped a 2x sharing factor. R14: prep emits
// fragment-ordered planes; each wave loads its OWN fragments straight to
// VGPRs (1 KB coalesced per wave-load), K-loop fully unrolled, zero barriers.
// Frag layout: plane[((g4*8 + kt)*2048) + u*512 + lane*8 + j]
//   g4 = row/64 (4-unit group), u = (row/16)%4, value = row g4*64+u*16+(l&15),
//   k = kt*32 + (l>>4)*8 + j.   One (g4,kt,u) slot = 1 KB, wave-contiguous.

typedef _Float16 half8 __attribute__((ext_vector_type(8)));
typedef float    floatx4 __attribute__((ext_vector_type(4)));

#define C_DIM 256
#define K_CODES 1024
#define HW 1024
#define NPIX 32768
#define NTILES 8          // 1024 / 128 candidate tiles per pixel

// ---------------- kernel 1: norm codebook  +  z transpose/split -------------
// blocks 0..1023: w-row normalize (numerics identical to verified rounds),
//   emit wfh/wfl in frag order (scattered 2B stores; 1 MB total, negligible).
// blocks 1024..1535: 64-pixel z tile: coalesced read, split, LDS transpose,
//   emit zfh/zfl in frag order (half8 stores, wave-contiguous 1 KB slots).
__global__ __launch_bounds__(256) void vq_prep(
        const float* __restrict__ z, const float* __restrict__ w,
        float* __restrict__ w_n, _Float16* __restrict__ wfh, _Float16* __restrict__ wfl,
        _Float16* __restrict__ zfh, _Float16* __restrict__ zfl) {
    __shared__ float wsum[4];
    __shared__ unsigned pk[64][257];   // h | l<<16 ; stride 257: 2-way-free writes
    const int t = threadIdx.x;

    if (blockIdx.x < K_CODES) {
        const int c = blockIdx.x;          // code row
        float x = w[c * C_DIM + t];
        float s = x * x;
        #pragma unroll
        for (int off = 32; off > 0; off >>= 1) s += __shfl_down(s, off, 64);
        if ((t & 63) == 0) wsum[t >> 6] = s;
        __syncthreads();
        float tot = wsum[0] + wsum[1] + wsum[2] + wsum[3];
        float inv = 1.0f / fmaxf(sqrtf(tot), 1e-12f);
        float y = x * inv;
        w_n[c * C_DIM + t] = y;            // row-major: finalize reads rows coalesced
        float ys = 16.0f * y;
        _Float16 hi = (_Float16)ys;
        _Float16 lo = (_Float16)(ys - (float)hi);
        // frag-order store: k = t -> kt = t>>5, lane = ((t>>3)&3)*16 + (c&15), j = t&7
        const int kt = t >> 5, l = ((t >> 3) & 3) * 16 + (c & 15), j = t & 7;
        const size_t fo = ((size_t)(c >> 6) * 8 + kt) * 2048 + ((c >> 4) & 3) * 512
                        + l * 8 + j;
        wfh[fo] = hi;
        wfl[fo] = lo;
        return;
    }

    const int zb = blockIdx.x - K_CODES;   // 0..511  == g4 group index
    const int pg = zb * 64;                // global pixel base
    const int b  = pg >> 10, p0 = pg & 1023;
    const float* zp = z + (size_t)b * C_DIM * HW + p0;

    // stage 1: read [16 c x 64 p] per iter, coalesced along p; split; LDS
    const int cc = t >> 4, pp = (t & 15) * 4;
    #pragma unroll
    for (int it = 0; it < 16; it++) {
        const int c = it * 16 + cc;
        floatx4 v = *(const floatx4*)(zp + (size_t)c * HW + pp);
        #pragma unroll
        for (int j = 0; j < 4; j++) {
            float xs = 4.0f * v[j];                 // same split path as R9-R13 ->
            _Float16 h = (_Float16)xs;              // bitwise-identical operands
            _Float16 l = (_Float16)(xs - (float)h);
            pk[pp + j][c] = (unsigned)__builtin_bit_cast(unsigned short, h)
                          | ((unsigned)__builtin_bit_cast(unsigned short, l) << 16);
        }
    }
    __syncthreads();

    // stage 2: frag-order emit. t = u*64 + lane; slot (zb, kt, u) is 1 KB,
    // lane's 16B at +lane*8 halves -> fully coalesced half8 stores.
    const int u = t >> 6, l = t & 63;
    const int row = u * 16 + (l & 15);
    #pragma unroll
    for (int kt = 0; kt < 8; kt++) {
        half8 hv, lv;
        #pragma unroll
        for (int j = 0; j < 8; j++) {
            unsigned v = pk[row][kt * 32 + (l >> 4) * 8 + j];
            hv[j] = __builtin_bit_cast(_Float16, (unsigned short)(v & 0xffffu));
            lv[j] = __builtin_bit_cast(_Float16, (unsigned short)(v >> 16));
        }
        const size_t fo = ((size_t)zb * 8 + kt) * 2048 + u * 512 + l * 8;
        *(half8*)(zfh + fo) = hv;
        *(half8*)(zfl + fo) = lv;
    }
}

// ---------------- kernel 2: barrier-free register-pipelined GEMM ------------
// grid (256 m-tiles, 8 n-tiles), 256 thr = 4 waves 2x2; wave tile 64x64.
// Per wave per kt: 16 coalesced half8 loads (own frags only), 48 MFMA.
// 2-deep register double-buffer, fully unrolled, compiler-counted vmcnt.
// No __shared__ in the loop, no barriers -> 8 free-running waves/CU.
__global__ __launch_bounds__(256, 2) void vq_gemm(
        const _Float16* __restrict__ zfh, const _Float16* __restrict__ zfl,
        const _Float16* __restrict__ wfh, const _Float16* __restrict__ wfl,
        float* __restrict__ cand_val, int* __restrict__ cand_idx) {
    __shared__ float red_v[128][2];
    __shared__ int   red_i[128][2];

    const int tid  = threadIdx.x;
    const int lane = tid & 63, wave = tid >> 6;
    const int wm = wave >> 1, wn = wave & 1;
    const int quad = lane >> 4, l15 = lane & 15;
    const int m0 = blockIdx.x * 128, n0 = blockIdx.y * 128;

    const size_t aoff = (size_t)(blockIdx.x * 2 + wm) * 8 * 2048 + lane * 8;
    const size_t boff = (size_t)(blockIdx.y * 2 + wn) * 8 * 2048 + lane * 8;
    const _Float16* pAh = zfh + aoff;
    const _Float16* pAl = zfl + aoff;
    const _Float16* pBh = wfh + boff;
    const _Float16* pBl = wfl + boff;

    floatx4 acc[4][4];
    #pragma unroll
    for (int i = 0; i < 4; i++)
        #pragma unroll
        for (int j = 0; j < 4; j++) acc[i][j] = (floatx4){0.f, 0.f, 0.f, 0.f};

    half8 A0h[4], A0l[4], B0h[4], B0l[4];
    half8 A1h[4], A1l[4], B1h[4], B1l[4];

#define LOADK(AH, AL, BH, BL, kt)                                              \
    {   _Pragma("unroll")                                                      \
        for (int i = 0; i < 4; i++) {                                          \
            AH[i] = *(const half8*)(pAh + (kt) * 2048 + i * 512);              \
            AL[i] = *(const half8*)(pAl + (kt) * 2048 + i * 512);              \
            BH[i] = *(const half8*)(pBh + (kt) * 2048 + i * 512);              \
            BL[i] = *(const half8*)(pBl + (kt) * 2048 + i * 512);              \
        }                                                                      \
    }

#define MFMAK(AH, AL, BH, BL)                                                  \
    {   _Pragma("unroll")                                                      \
        for (int mi = 0; mi < 4; mi++)                                         \
            _Pragma("unroll")                                                  \
            for (int ni = 0; ni < 4; ni++) {                                   \
                acc[mi][ni] = __builtin_amdgcn_mfma_f32_16x16x32_f16(          \
                    AH[mi], BH[ni], acc[mi][ni], 0, 0, 0);                     \
                acc[mi][ni] = __builtin_amdgcn_mfma_f32_16x16x32_f16(          \
                    AH[mi], BL[ni], acc[mi][ni], 0, 0, 0);                     \
                acc[mi][ni] = __builtin_amdgcn_mfma_f32_16x16x32_f16(          \
                    AL[mi], BH[ni], acc[mi][ni], 0, 0, 0);                     \
            }                                                                  \
    }

    LOADK(A0h, A0l, B0h, B0l, 0);
    LOADK(A1h, A1l, B1h, B1l, 1);  MFMAK(A0h, A0l, B0h, B0l);
    LOADK(A0h, A0l, B0h, B0l, 2);  MFMAK(A1h, A1l, B1h, B1l);
    LOADK(A1h, A1l, B1h, B1l, 3);  MFMAK(A0h, A0l, B0h, B0l);
    LOADK(A0h, A0l, B0h, B0l, 4);  MFMAK(A1h, A1l, B1h, B1l);
    LOADK(A1h, A1l, B1h, B1l, 5);  MFMAK(A0h, A0l, B0h, B0l);
    LOADK(A0h, A0l, B0h, B0l, 6);  MFMAK(A1h, A1l, B1h, B1l);
    LOADK(A1h, A1l, B1h, B1l, 7);  MFMAK(A0h, A0l, B0h, B0l);
                                   MFMAK(A1h, A1l, B1h, B1l);
#undef LOADK
#undef MFMAK

    // epilogue: per-lane best over ni, shfl-reduce over quad's 16 lanes
    #pragma unroll
    for (int mi = 0; mi < 4; mi++) {
        #pragma unroll
        for (int r = 0; r < 4; r++) {
            float bv = -__builtin_inff();
            int   bi = 0x7fffffff;
            #pragma unroll
            for (int ni = 0; ni < 4; ni++) {
                float v = acc[mi][ni][r];
                int  ci = n0 + wn * 64 + ni * 16 + l15;
                if (v > bv || (v == bv && ci < bi)) { bv = v; bi = ci; }
            }
            #pragma unroll
            for (int mk = 8; mk; mk >>= 1) {
                float ov = __shfl_xor(bv, mk, 16);
                int   oi = __shfl_xor(bi, mk, 16);
                if (ov > bv || (ov == bv && oi < bi)) { bv = ov; bi = oi; }
            }
            if (l15 == 0) {
                int row = wm * 64 + mi * 16 + quad * 4 + r;  // C/D: row=(lane>>4)*4+reg
                red_v[row][wn] = bv;
                red_i[row][wn] = bi;
            }
        }
    }
    __syncthreads();
    if (tid < 128) {
        float bv = red_v[tid][0]; int bi = red_i[tid][0];
        float v2 = red_v[tid][1]; int i2 = red_i[tid][1];
        if (v2 > bv || (v2 == bv && i2 < bi)) { bv = v2; bi = i2; }
        const int pix = m0 + tid;
        cand_val[(size_t)pix * NTILES + blockIdx.y] = bv;
        cand_idx[(size_t)pix * NTILES + blockIdx.y] = bi;
    }
}

// ---------------- kernel 3: gather-free finalize (unchanged, verified) ------
__global__ __launch_bounds__(256) void vq_finalize(
        const float* __restrict__ cand_val,
        const int*   __restrict__ cand_idx,
        const float* __restrict__ w_n,   // [1024][256] row-major
        float* __restrict__ zq,          // [32][256][1024]
        float* __restrict__ idx_out) {   // [32768] as float
    __shared__ float tile[64][257];      // 65.8 KB, +1 pad -> conflict-free
    __shared__ int   idx_s[64];
    const int t    = threadIdx.x;
    const int lane = t & 63, wave = t >> 6;
    const int n0   = blockIdx.x * 64;    // global pixel base
    const int b    = n0 >> 10, p0 = n0 & 1023;

    if (t < 64) {
        const int n = n0 + t;
        const size_t base = (size_t)n * NTILES;
        float bv = cand_val[base]; int bi = cand_idx[base];
        #pragma unroll
        for (int j = 1; j < NTILES; j++) {
            float v = cand_val[base + j];
            int   c = cand_idx[base + j];
            if (v > bv || (v == bv && c < bi)) { bv = v; bi = c; }
        }
        idx_s[t] = bi;
        idx_out[n] = (float)bi;
    }
    __syncthreads();
    // (b) wave w loads rows for pixels w*16..+15: 1 KB coalesced per row
    #pragma unroll
    for (int i = 0; i < 16; i++) {
        const int p = wave * 16 + i;
        const int row = idx_s[p];        // wave-uniform broadcast
        floatx4 v = *(const floatx4*)(w_n + (size_t)row * C_DIM + lane * 4);
        *(floatx4*)&tile[p][lane * 4] = v;
    }
    __syncthreads();
    // (c) stores: float4 along pixels; per wave-store 4 c-values x 64 px
    float* zqb = zq + (size_t)b * (C_DIM * HW) + p0;
    #pragma unroll
    for (int it = 0; it < 16; it++) {
        const int c = it * 16 + wave * 4 + (lane >> 4);   // 0..255
        const int p = (lane & 15) * 4;
        floatx4 v = { tile[p][c], tile[p + 1][c], tile[p + 2][c], tile[p + 3][c] };
        *(floatx4*)(zqb + (size_t)c * HW + p) = v;
    }
}

// ---------------- launcher --------------------------------------------------
extern "C" void kernel_launch(void* const* d_in, const int* in_sizes, int n_in,
                              void* d_out, int out_size, void* d_ws, size_t ws_size,
                              hipStream_t stream) {
    const float* z = (const float*)d_in[0];   // 32*256*32*32
    const float* w = (const float*)d_in[1];   // 1024*256
    float* out     = (float*)d_out;           // z_q (8388608) ++ indices (32768)

    char* ws = (char*)d_ws;                              // 36 MB used
    _Float16* zfh  = (_Float16*)(ws);                    //  0 .. 16 MB
    _Float16* zfl  = (_Float16*)(ws + (16u << 20));      // 16 .. 32 MB
    float*    w_n  = (float*)(ws + (32u << 20));         // 32 .. 33 MB
    _Float16* wfh  = (_Float16*)(ws + (33u << 20));      // 33 .. 33.5 MB
    _Float16* wfl  = (_Float16*)(ws + (33u << 20) + (1u << 19)); // 33.5 .. 34 MB
    float*    cval = (float*)(ws + (34u << 20));         // 34 .. 35 MB
    int*      cidx = (int*)(ws + (35u << 20));           // 35 .. 36 MB

    vq_prep<<<K_CODES + NPIX / 64, 256, 0, stream>>>(z, w, w_n, wfh, wfl, zfh, zfl);
    vq_gemm<<<dim3(NPIX / 128, NTILES), 256, 0, stream>>>(zfh, zfl, wfh, wfl, cval, cidx);
    vq_finalize<<<NPIX / 64, 256, 0, stream>>>(cval, cidx, w_n, out, out + 8388608);
}